// Round 7
// baseline (201.543 us; speedup 1.0000x reference)
//
#include <hip/hip_runtime.h>
#include <stdint.h>

// LinearAttention on MI355X — round 7: 8 launches, softmax folded into k1/k3_sum.
//   Kexp = exp(W_k·x)  (no max-subtract; |k|<~6 so f32 exp is safe)
//   rs[b][r] = sum_n Kexp  (f32, atomics from k1 epilogue)
//   G_b = (Kexp_b · x_b^T) / rs   (512x256 per b, split-K=4)
//   U[h] = W_out_h · W_v_h^T  (batch-independent, direct f32 GEMM)
//   M_b[o][hd] = sum_c U[h][o][c]·G_b[hd][c];  N_b = M_b·W_q;  out = N_b·x_b + bias
//
// ws layout (bytes):
//   Kexp bf16 [8][512][4096]   @ 0          (33,554,432)
//   xbT  bf16 [8][4096][256]   @ 33554432   (16,777,216)
//   xbc  bf16 [8][256][4096]   @ 50331648   (16,777,216)
//   wkb  bf16 [512][256]       @ 67108864   (   262,144)
//   wqT  bf16 [256][512]       @ 67371008   (   262,144)
//   U    bf16 [4][256][256]    @ 67633152   (   524,288)
//   rs   f32  [8][512]         @ 68157440   (    16,384)
//   Gp   f32  [4][8][512][256] @ 68173824   (16,777,216)
//   G    bf16 [8][512][256]    @ 84951040   ( 2,097,152)
//   Mb   bf16 [8][256][512]    @ 87048192   ( 2,097,152)
//   Nb   bf16 [8][256][256]    @ 89145344   ( 1,048,576)
// total 90,193,920 B

using frag8 = __attribute__((ext_vector_type(8))) short;   // 8 x bf16
using f32x4 = __attribute__((ext_vector_type(4))) float;

__device__ __forceinline__ float bf2f(unsigned short u) {
    union { unsigned int u; float f; } c;
    c.u = ((unsigned int)u) << 16;
    return c.f;
}
__device__ __forceinline__ unsigned short f2bf(float f) {
    union { float f; unsigned int u; } c; c.f = f;
    unsigned int u = c.u;
    return (unsigned short)((u + 0x7FFFu + ((u >> 16) & 1u)) >> 16);
}

__device__ __forceinline__ void gl_lds16(const void* g, void* l) {
    __builtin_amdgcn_global_load_lds(
        (const __attribute__((address_space(1))) unsigned int*)g,
        (__attribute__((address_space(3))) unsigned int*)l, 16, 0, 0);
}

// --- k0_weights: wkb copy | wqT transpose | U = Wout_h·Wv_h^T | rs zero ----
__global__ __launch_bounds__(256) void k0_weights(
    const float* __restrict__ w_qkv, const float* __restrict__ w_out,
    unsigned short* __restrict__ wkb, unsigned short* __restrict__ wqT,
    unsigned short* __restrict__ U, float* __restrict__ rs)
{
    __shared__ float T[64][65];
    const int blk = blockIdx.x;
    const int tid = threadIdx.x;
    if (blk < 128) {                 // wkb: w_qkv rows 512..1024 -> bf16
        const int idx = (blk * 256 + tid) * 4;
        float4 v = *(const float4*)(w_qkv + 512 * 256 + idx);
        ushort4 o;
        o.x = f2bf(v.x); o.y = f2bf(v.y); o.z = f2bf(v.z); o.w = f2bf(v.w);
        *(ushort4*)(wkb + idx) = o;
    } else if (blk < 160) {          // wqT[c][j] = bf16(w_qkv[j][c]), j<512
        const int t = blk - 128;     // 8 j-tiles x 4 c-tiles
        const int j0 = (t >> 2) * 64, c0 = (t & 3) * 64;
        const int r = tid >> 4, cc = (tid & 15) * 4;
        #pragma unroll
        for (int p = 0; p < 4; ++p) {
            float4 v = *(const float4*)(w_qkv + (j0 + r + p * 16) * 256 + c0 + cc);
            T[r + p * 16][cc + 0] = v.x; T[r + p * 16][cc + 1] = v.y;
            T[r + p * 16][cc + 2] = v.z; T[r + p * 16][cc + 3] = v.w;
        }
        __syncthreads();
        const int c = tid >> 2, jj = (tid & 3) * 16;
        #pragma unroll
        for (int g = 0; g < 4; ++g) {
            ushort4 o;
            o.x = f2bf(T[jj + g * 4 + 0][c]);
            o.y = f2bf(T[jj + g * 4 + 1][c]);
            o.z = f2bf(T[jj + g * 4 + 2][c]);
            o.w = f2bf(T[jj + g * 4 + 3][c]);
            *(ushort4*)(wqT + (c0 + c) * 512 + j0 + jj + g * 4) = o;
        }
    } else if (blk < 224) {          // U[h][o][c] = sum_e w_out[o][h*128+e]*w_qkv[1024+h*128+e][c]
        float (*As)[65] = &T[0];     // [e][o] 16x64
        float (*Bs)[65] = &T[16];    // [e][c] 16x64
        const int ub = blk - 160;
        const int h = ub >> 4, rem = ub & 15;
        const int o0 = (rem >> 2) * 64, c0 = (rem & 3) * 64;
        const int tm = tid >> 4, tn = tid & 15;
        const int ar = tid >> 2, ac = (tid & 3) * 4;
        const int br = tid >> 4, bc = (tid & 15) * 4;
        float acc[4][4] = {};
        for (int e0 = 0; e0 < 128; e0 += 16) {
            float4 a4 = *(const float4*)(w_out + (o0 + ar) * 512 + h * 128 + e0 + ac);
            float4 b4 = *(const float4*)(w_qkv + (1024 + h * 128 + e0 + br) * 256 + c0 + bc);
            __syncthreads();
            As[ac + 0][ar] = a4.x; As[ac + 1][ar] = a4.y;
            As[ac + 2][ar] = a4.z; As[ac + 3][ar] = a4.w;
            Bs[br][bc + 0] = b4.x; Bs[br][bc + 1] = b4.y;
            Bs[br][bc + 2] = b4.z; Bs[br][bc + 3] = b4.w;
            __syncthreads();
            #pragma unroll
            for (int kk = 0; kk < 16; ++kk) {
                float a[4], bb[4];
                #pragma unroll
                for (int i = 0; i < 4; ++i) a[i] = As[kk][tm * 4 + i];
                #pragma unroll
                for (int j = 0; j < 4; ++j) bb[j] = Bs[kk][tn * 4 + j];
                #pragma unroll
                for (int i = 0; i < 4; ++i)
                    #pragma unroll
                    for (int j = 0; j < 4; ++j) acc[i][j] += a[i] * bb[j];
            }
        }
        #pragma unroll
        for (int i = 0; i < 4; ++i) {
            ushort4 o;
            o.x = f2bf(acc[i][0]); o.y = f2bf(acc[i][1]);
            o.z = f2bf(acc[i][2]); o.w = f2bf(acc[i][3]);
            *(ushort4*)(U + h * 65536 + (o0 + tm * 4 + i) * 256 + c0 + tn * 4) = o;
        }
    } else {                         // zero rs (4096 floats over 4 blocks)
        const int idx = ((blk - 224) * 256 + tid) * 4;
        *(float4*)(rs + idx) = make_float4(0.f, 0.f, 0.f, 0.f);
    }
}

// ------ k0_xt: xbT[b][n][c] = bf16(x[b][c][n]);  xbc[b][c][n] = bf16(x) ----
__global__ __launch_bounds__(256) void k0_xt(
    const float* __restrict__ x, unsigned short* __restrict__ xbT,
    unsigned short* __restrict__ xbc)
{
    __shared__ float T[64][65];
    const int tid = threadIdx.x;
    const int n0 = blockIdx.x * 64, c0 = blockIdx.y * 64, b = blockIdx.z;
    const float* xb = x + (size_t)b * 1048576;
    const int cr = tid >> 4, nc = (tid & 15) * 4;
    #pragma unroll
    for (int p = 0; p < 4; ++p) {
        float4 v = *(const float4*)(xb + (size_t)(c0 + cr + p * 16) * 4096 + n0 + nc);
        T[cr + p * 16][nc + 0] = v.x; T[cr + p * 16][nc + 1] = v.y;
        T[cr + p * 16][nc + 2] = v.z; T[cr + p * 16][nc + 3] = v.w;
        ushort4 o;
        o.x = f2bf(v.x); o.y = f2bf(v.y); o.z = f2bf(v.z); o.w = f2bf(v.w);
        *(ushort4*)(xbc + (size_t)b * 1048576 + (size_t)(c0 + cr + p * 16) * 4096 + n0 + nc) = o;
    }
    __syncthreads();
    const int n = tid >> 2, cc = (tid & 3) * 16;
    unsigned short* dst = xbT + (size_t)b * 1048576 + (size_t)(n0 + n) * 256 + c0 + cc;
    #pragma unroll
    for (int g = 0; g < 4; ++g) {
        ushort4 o;
        o.x = f2bf(T[cc + g * 4 + 0][n]);
        o.y = f2bf(T[cc + g * 4 + 1][n]);
        o.z = f2bf(T[cc + g * 4 + 2][n]);
        o.w = f2bf(T[cc + g * 4 + 3][n]);
        *(ushort4*)(dst + g * 4) = o;
    }
}

// -------- MFMA gemm_bt: C[m][n] = sum_k A[m][k] * B[n][k]  (bf16 in) -------
// 128x128 block tile, BK=32, 4 waves (each 64x64), 16x16x32 bf16 MFMA.
// MODE 0: C bf16, z-strided (k5).
// MODE 1: C f32 + bias[row] (k6).
// MODE 3: kM — A=U[h], B=G[b] rows h*128.., C=Mb[b] cols h*128.., K=256.
// MODE 4: k3G split-K — k-slice = (bx>>1)*1024, n0=(bx&1)*128, C f32 partials.
// MODE 5: k1 — C = bf16(exp(acc)), rowsum atomics into aux (rs).
template<int MODE>
__global__ __launch_bounds__(256) void mfma_bt(
    const unsigned short* __restrict__ A0, int lda,
    const unsigned short* __restrict__ B0, int ldb,
    void* __restrict__ C0, int ldc,
    const float* __restrict__ bias, int Kp,
    unsigned long long sAz, unsigned long long sBz, unsigned long long sCz,
    float* __restrict__ aux)
{
    __shared__ unsigned short As[128 * 32];
    __shared__ unsigned short Bs[128 * 32];
    const int tid  = threadIdx.x;
    const int w    = tid >> 6, lane = tid & 63;
    const int quad = lane >> 4, l16 = lane & 15;
    const int wm = (w >> 1) * 64, wn = (w & 1) * 64;
    const int z = blockIdx.z;

    const unsigned short* A;
    const unsigned short* B;
    int ks, ke, m0, n0;
    if constexpr (MODE == 3) {
        m0 = blockIdx.y * 128; n0 = 0;
        ks = 0; ke = 256;
        A = A0 + (unsigned long long)(z & 3) * 65536ull + (unsigned long long)m0 * lda;
        B = B0 + (unsigned long long)(z >> 2) * 131072ull + (unsigned long long)(z & 3) * 32768ull;
    } else if constexpr (MODE == 4) {
        m0 = blockIdx.y * 128; n0 = (blockIdx.x & 1) * 128;
        ks = (blockIdx.x >> 1) * 1024; ke = ks + 1024;
        A = A0 + sAz * z + (unsigned long long)m0 * lda;
        B = B0 + sBz * z + (unsigned long long)n0 * ldb;
    } else {
        m0 = blockIdx.y * 128; n0 = blockIdx.x * 128;
        ks = 0; ke = Kp;
        A = A0 + sAz * z + (unsigned long long)m0 * lda;
        B = B0 + sBz * z + (unsigned long long)n0 * ldb;
    }

    // staging: 512 chunks of 16B per tile; wave w handles chunks [w*128, w*128+128)
    const int cA0 = w * 128 + lane;
    const int cA1 = cA0 + 64;
    const unsigned short* gA0 = A + (unsigned long long)(cA0 >> 2) * lda + (cA0 & 3) * 8;
    const unsigned short* gA1 = A + (unsigned long long)(cA1 >> 2) * lda + (cA1 & 3) * 8;
    const unsigned short* gB0 = B + (unsigned long long)(cA0 >> 2) * ldb + (cA0 & 3) * 8;
    const unsigned short* gB1 = B + (unsigned long long)(cA1 >> 2) * ldb + (cA1 & 3) * 8;
    unsigned short* lA0 = As + w * 1024;
    unsigned short* lA1 = As + w * 1024 + 512;
    unsigned short* lB0 = Bs + w * 1024;
    unsigned short* lB1 = Bs + w * 1024 + 512;

    f32x4 acc[4][4] = {};

    for (int k0 = ks; k0 < ke; k0 += 32) {
        gl_lds16(gA0 + k0, lA0);
        gl_lds16(gA1 + k0, lA1);
        gl_lds16(gB0 + k0, lB0);
        gl_lds16(gB1 + k0, lB1);
        __syncthreads();
        frag8 a[4], b[4];
        #pragma unroll
        for (int t = 0; t < 4; ++t) {
            a[t] = *(const frag8*)(As + (wm + t * 16 + l16) * 32 + quad * 8);
            b[t] = *(const frag8*)(Bs + (wn + t * 16 + l16) * 32 + quad * 8);
        }
        #pragma unroll
        for (int mt = 0; mt < 4; ++mt)
            #pragma unroll
            for (int nt = 0; nt < 4; ++nt)
                acc[mt][nt] = __builtin_amdgcn_mfma_f32_16x16x32_bf16(
                    a[mt], b[nt], acc[mt][nt], 0, 0, 0);
        __syncthreads();
    }

    // epilogue: C/D mapping col = lane&15, row = quad*4 + reg  [m91-verified]
    if constexpr (MODE == 0 || MODE == 3) {
        unsigned short* C;
        if constexpr (MODE == 0)
            C = (unsigned short*)C0 + sCz * z + (unsigned long long)m0 * ldc + n0;
        else
            C = (unsigned short*)C0 + (unsigned long long)(z >> 2) * 131072ull
              + (unsigned long long)(z & 3) * 128ull + (unsigned long long)m0 * ldc;
        #pragma unroll
        for (int mt = 0; mt < 4; ++mt) {
            const int row = wm + mt * 16 + quad * 4;
            #pragma unroll
            for (int nt = 0; nt < 4; ++nt) {
                const int col = wn + nt * 16 + l16;
                #pragma unroll
                for (int r = 0; r < 4; ++r)
                    C[(unsigned long long)(row + r) * ldc + col] = f2bf(acc[mt][nt][r]);
            }
        }
    } else if constexpr (MODE == 1) {
        float* C = (float*)C0 + sCz * z + (unsigned long long)m0 * ldc + n0;
        const float* bp = bias + m0;
        #pragma unroll
        for (int mt = 0; mt < 4; ++mt) {
            const int row = wm + mt * 16 + quad * 4;
            #pragma unroll
            for (int nt = 0; nt < 4; ++nt) {
                const int col = wn + nt * 16 + l16;
                #pragma unroll
                for (int r = 0; r < 4; ++r)
                    C[(unsigned long long)(row + r) * ldc + col] = acc[mt][nt][r] + bp[row + r];
            }
        }
    } else if constexpr (MODE == 4) {
        float* C = (float*)C0 + (unsigned long long)(blockIdx.x >> 1) * 1048576ull
                 + sCz * z + (unsigned long long)m0 * ldc + n0;
        #pragma unroll
        for (int mt = 0; mt < 4; ++mt) {
            const int row = wm + mt * 16 + quad * 4;
            #pragma unroll
            for (int nt = 0; nt < 4; ++nt) {
                const int col = wn + nt * 16 + l16;
                #pragma unroll
                for (int r = 0; r < 4; ++r)
                    C[(unsigned long long)(row + r) * ldc + col] = acc[mt][nt][r];
            }
        }
    } else {  // MODE 5: Kexp + rowsum atomics
        unsigned short* C = (unsigned short*)C0 + sCz * z
                          + (unsigned long long)m0 * ldc + n0;
        float rp[4][4] = {};
        #pragma unroll
        for (int mt = 0; mt < 4; ++mt) {
            const int row = wm + mt * 16 + quad * 4;
            #pragma unroll
            for (int nt = 0; nt < 4; ++nt) {
                const int col = wn + nt * 16 + l16;
                #pragma unroll
                for (int r = 0; r < 4; ++r) {
                    const float e = __expf(acc[mt][nt][r]);
                    C[(unsigned long long)(row + r) * ldc + col] = f2bf(e);
                    rp[mt][r] += e;
                }
            }
        }
        #pragma unroll
        for (int m = 1; m < 16; m <<= 1)
            #pragma unroll
            for (int mt = 0; mt < 4; ++mt)
                #pragma unroll
                for (int r = 0; r < 4; ++r)
                    rp[mt][r] += __shfl_xor(rp[mt][r], m, 64);
        if (l16 == 0) {
            float* rsb = aux + z * 512 + m0;
            #pragma unroll
            for (int mt = 0; mt < 4; ++mt)
                #pragma unroll
                for (int r = 0; r < 4; ++r)
                    atomicAdd(rsb + wm + mt * 16 + quad * 4 + r, rp[mt][r]);
        }
    }
}

// ------- k3_sum: G[i] = bf16( (sum_s Gp[s][i]) / rs[row] ), i < 1048576 ----
__global__ __launch_bounds__(256) void k3_sum(
    const float* __restrict__ Gp, const float* __restrict__ rs,
    unsigned short* __restrict__ G)
{
    const int idx = (blockIdx.x * 256 + threadIdx.x) * 4;
    const float inv = 1.0f / rs[idx >> 8];
    float4 s = make_float4(0.f, 0.f, 0.f, 0.f);
    #pragma unroll
    for (int sl = 0; sl < 4; ++sl) {
        float4 t = *(const float4*)(Gp + (size_t)sl * 1048576 + idx);
        s.x += t.x; s.y += t.y; s.z += t.z; s.w += t.w;
    }
    ushort4 o;
    o.x = f2bf(s.x * inv); o.y = f2bf(s.y * inv);
    o.z = f2bf(s.z * inv); o.w = f2bf(s.w * inv);
    *(ushort4*)(G + idx) = o;
}

extern "C" void kernel_launch(void* const* d_in, const int* in_sizes, int n_in,
                              void* d_out, int out_size, void* d_ws, size_t ws_size,
                              hipStream_t stream) {
    (void)in_sizes; (void)n_in; (void)out_size; (void)ws_size;
    const float* x     = (const float*)d_in[0];  // f32 [8,256,64,64]
    const float* w_qkv = (const float*)d_in[1];  // f32 [1536,256]
    const float* w_out = (const float*)d_in[2];  // f32 [256,512]
    const float* b_out = (const float*)d_in[3];  // f32 [256]
    float* out = (float*)d_out;                  // f32 [8,256,64,64]

    char* ws = (char*)d_ws;
    unsigned short* Kexp = (unsigned short*)ws;                 // 33,554,432
    unsigned short* xbT  = (unsigned short*)(ws + 33554432);    // 16,777,216
    unsigned short* xbc  = (unsigned short*)(ws + 50331648);    // 16,777,216
    unsigned short* wkb  = (unsigned short*)(ws + 67108864);    //    262,144
    unsigned short* wqT  = (unsigned short*)(ws + 67371008);    //    262,144
    unsigned short* U    = (unsigned short*)(ws + 67633152);    //    524,288
    float*          rs   = (float*)(ws + 68157440);             //     16,384
    float*          Gp   = (float*)(ws + 68173824);             // 16,777,216
    unsigned short* G    = (unsigned short*)(ws + 84951040);    //  2,097,152
    unsigned short* Mb   = (unsigned short*)(ws + 87048192);    //  2,097,152
    unsigned short* Nb   = (unsigned short*)(ws + 89145344);    //  1,048,576

    k0_weights<<<dim3(228), 256, 0, stream>>>(w_qkv, w_out, wkb, wqT, U, rs);
    k0_xt<<<dim3(64, 4, 8), 256, 0, stream>>>(x, xbT, xbc);
    // k1: Kexp[b][r][n] = exp( sum_c wkb[r][c] * xbT[b][n][c] ), rs += rowsums
    mfma_bt<5><<<dim3(32, 4, 8), 256, 0, stream>>>(
        wkb, 256, xbT, 256, Kexp, 4096, nullptr, 256,
        0ull, 1048576ull, 2097152ull, rs);
    // k3G: Gp[ks][b][hd][c] = sum_{n in slice} Kexp[b][hd][n] * xbc[b][c][n]
    mfma_bt<4><<<dim3(8, 4, 8), 256, 0, stream>>>(
        Kexp, 4096, xbc, 4096, Gp, 256, nullptr, 0,
        2097152ull, 1048576ull, 131072ull, nullptr);
    k3_sum<<<dim3(1024), 256, 0, stream>>>(Gp, rs, G);
    // kM: Mb[b][o][h*128+d] = sum_c U[h][o][c] * G[b][h*128+d][c]
    mfma_bt<3><<<dim3(1, 2, 32), 256, 0, stream>>>(
        U, 256, G, 256, Mb, 512, nullptr, 256,
        0ull, 0ull, 0ull, nullptr);
    // k5: Nb[b][o][c] = sum_j Mb[b][o][j] * wqT[c][j]
    mfma_bt<0><<<dim3(2, 2, 8), 256, 0, stream>>>(
        Mb, 512, wqT, 512, Nb, 256, nullptr, 512,
        131072ull, 0ull, 65536ull, nullptr);
    // k6: out[b][o][n] = sum_c Nb[b][o][c] * xbT[b][n][c] + b_out[o]
    mfma_bt<1><<<dim3(32, 2, 8), 256, 0, stream>>>(
        Nb, 256, xbT, 256, out, 4096, b_out, 256,
        65536ull, 1048576ull, 1048576ull, nullptr);
}

// Round 8
// 198.167 us; speedup vs baseline: 1.0170x; 1.0170x over previous
//
#include <hip/hip_runtime.h>
#include <stdint.h>

// LinearAttention on MI355X — round 8: BK=64 K-loops, LDS-coalesced epilogues,
// merged k0. Pipeline:
//   Kexp = exp(W_k·x); rs = rowsums (atomics)
//   Gp_s = Kexp·x^T (split-4);  G = (sum Gp)/rs
//   U[h] = W_out_h·W_v_h^T;  M = U·G^T;  N = M·W_q;  out = N·x + bias
//
// ws layout (bytes):
//   Kexp bf16 [8][512][4096]   @ 0          (33,554,432)
//   xbT  bf16 [8][4096][256]   @ 33554432   (16,777,216)
//   xbc  bf16 [8][256][4096]   @ 50331648   (16,777,216)
//   wkb  bf16 [512][256]       @ 67108864   (   262,144)
//   wqT  bf16 [256][512]       @ 67371008   (   262,144)
//   U    bf16 [4][256][256]    @ 67633152   (   524,288)
//   rs   f32  [8][512]         @ 68157440   (    16,384)
//   Gp   f32  [4][8][512][256] @ 68173824   (16,777,216)
//   G    bf16 [8][512][256]    @ 84951040   ( 2,097,152)
//   Mb   bf16 [8][256][512]    @ 87048192   ( 2,097,152)
//   Nb   bf16 [8][256][256]    @ 89145344   ( 1,048,576)

using frag8 = __attribute__((ext_vector_type(8))) short;   // 8 x bf16
using f32x4 = __attribute__((ext_vector_type(4))) float;
typedef unsigned short us8 __attribute__((ext_vector_type(8)));

__device__ __forceinline__ float bf2f(unsigned short u) {
    union { unsigned int u; float f; } c;
    c.u = ((unsigned int)u) << 16;
    return c.f;
}
__device__ __forceinline__ unsigned short f2bf(float f) {
    union { float f; unsigned int u; } c; c.f = f;
    unsigned int u = c.u;
    return (unsigned short)((u + 0x7FFFu + ((u >> 16) & 1u)) >> 16);
}

__device__ __forceinline__ void gl_lds16(const void* g, void* l) {
    __builtin_amdgcn_global_load_lds(
        (const __attribute__((address_space(1))) unsigned int*)g,
        (__attribute__((address_space(3))) unsigned int*)l, 16, 0, 0);
}

// ---- k0_all: [0,512) xbT transpose | [512,1024) xbc copy | [1024,1252) wts -
__global__ __launch_bounds__(256) void k0_all(
    const float* __restrict__ x, const float* __restrict__ w_qkv,
    const float* __restrict__ w_out,
    unsigned short* __restrict__ xbT, unsigned short* __restrict__ xbc,
    unsigned short* __restrict__ wkb, unsigned short* __restrict__ wqT,
    unsigned short* __restrict__ U, float* __restrict__ rs)
{
    __shared__ __align__(16) unsigned char sm[68096];   // 128*133*4
    const int blk = blockIdx.x;
    const int tid = threadIdx.x;
    if (blk < 512) {                 // xbT[b][n][c] = bf16(x[b][c][n]), 128x128 tiles
        float (*T)[133] = (float(*)[133])sm;
        const int b = blk >> 6, rem = blk & 63;
        const int n0 = (rem >> 1) * 128, c0 = (rem & 1) * 128;
        const float* xb = x + (size_t)b * 1048576;
        const int rr = tid >> 5, cc4 = (tid & 31) * 4;
        #pragma unroll
        for (int p = 0; p < 16; ++p) {
            const int r = rr + p * 8;
            float4 v = *(const float4*)(xb + (size_t)(c0 + r) * 4096 + n0 + cc4);
            T[r][cc4 + 0] = v.x; T[r][cc4 + 1] = v.y;
            T[r][cc4 + 2] = v.z; T[r][cc4 + 3] = v.w;
        }
        __syncthreads();
        const int nr = tid >> 4, c8 = (tid & 15) * 8;
        unsigned short* dst = xbT + (size_t)b * 1048576 + (size_t)n0 * 256 + c0;
        #pragma unroll
        for (int p = 0; p < 8; ++p) {
            const int n = nr + p * 16;
            us8 o;
            #pragma unroll
            for (int j = 0; j < 8; ++j) o[j] = f2bf(T[c8 + j][n]);
            *(us8*)(dst + (size_t)n * 256 + c8) = o;
        }
    } else if (blk < 1024) {         // xbc = bf16(x), straight copy
        const int base = (blk - 512) * 16384;
        #pragma unroll
        for (int p = 0; p < 8; ++p) {
            const int idx = base + p * 2048 + tid * 8;
            float4 a = *(const float4*)(x + idx);
            float4 b = *(const float4*)(x + idx + 4);
            us8 o;
            o[0] = f2bf(a.x); o[1] = f2bf(a.y); o[2] = f2bf(a.z); o[3] = f2bf(a.w);
            o[4] = f2bf(b.x); o[5] = f2bf(b.y); o[6] = f2bf(b.z); o[7] = f2bf(b.w);
            *(us8*)(xbc + idx) = o;
        }
    } else {
        const int wb = blk - 1024;
        if (wb < 128) {              // wkb: w_qkv rows 512..1024 -> bf16
            const int idx = (wb * 256 + tid) * 4;
            float4 v = *(const float4*)(w_qkv + 512 * 256 + idx);
            ushort4 o;
            o.x = f2bf(v.x); o.y = f2bf(v.y); o.z = f2bf(v.z); o.w = f2bf(v.w);
            *(ushort4*)(wkb + idx) = o;
        } else if (wb < 160) {       // wqT[c][j] = bf16(w_qkv[j][c]), j<512
            float (*T)[65] = (float(*)[65])sm;
            const int t = wb - 128;
            const int j0 = (t >> 2) * 64, c0 = (t & 3) * 64;
            const int r = tid >> 4, cc = (tid & 15) * 4;
            #pragma unroll
            for (int p = 0; p < 4; ++p) {
                float4 v = *(const float4*)(w_qkv + (j0 + r + p * 16) * 256 + c0 + cc);
                T[r + p * 16][cc + 0] = v.x; T[r + p * 16][cc + 1] = v.y;
                T[r + p * 16][cc + 2] = v.z; T[r + p * 16][cc + 3] = v.w;
            }
            __syncthreads();
            const int c = tid >> 2, jj = (tid & 3) * 16;
            #pragma unroll
            for (int g = 0; g < 4; ++g) {
                ushort4 o;
                o.x = f2bf(T[jj + g * 4 + 0][c]);
                o.y = f2bf(T[jj + g * 4 + 1][c]);
                o.z = f2bf(T[jj + g * 4 + 2][c]);
                o.w = f2bf(T[jj + g * 4 + 3][c]);
                *(ushort4*)(wqT + (c0 + c) * 512 + j0 + jj + g * 4) = o;
            }
        } else if (wb < 224) {       // U[h][o][c] = sum_e w_out[o][h*128+e]*w_qkv[1024+h*128+e][c]
            float (*T)[65] = (float(*)[65])sm;
            float (*As)[65] = &T[0];
            float (*Bs)[65] = &T[16];
            const int ub = wb - 160;
            const int h = ub >> 4, rem = ub & 15;
            const int o0 = (rem >> 2) * 64, c0 = (rem & 3) * 64;
            const int tm = tid >> 4, tn = tid & 15;
            const int ar = tid >> 2, ac = (tid & 3) * 4;
            const int br = tid >> 4, bc = (tid & 15) * 4;
            float acc[4][4] = {};
            for (int e0 = 0; e0 < 128; e0 += 16) {
                float4 a4 = *(const float4*)(w_out + (o0 + ar) * 512 + h * 128 + e0 + ac);
                float4 b4 = *(const float4*)(w_qkv + (1024 + h * 128 + e0 + br) * 256 + c0 + bc);
                __syncthreads();
                As[ac + 0][ar] = a4.x; As[ac + 1][ar] = a4.y;
                As[ac + 2][ar] = a4.z; As[ac + 3][ar] = a4.w;
                Bs[br][bc + 0] = b4.x; Bs[br][bc + 1] = b4.y;
                Bs[br][bc + 2] = b4.z; Bs[br][bc + 3] = b4.w;
                __syncthreads();
                #pragma unroll
                for (int kk = 0; kk < 16; ++kk) {
                    float a[4], bb[4];
                    #pragma unroll
                    for (int i = 0; i < 4; ++i) a[i] = As[kk][tm * 4 + i];
                    #pragma unroll
                    for (int j = 0; j < 4; ++j) bb[j] = Bs[kk][tn * 4 + j];
                    #pragma unroll
                    for (int i = 0; i < 4; ++i)
                        #pragma unroll
                        for (int j = 0; j < 4; ++j) acc[i][j] += a[i] * bb[j];
                }
            }
            #pragma unroll
            for (int i = 0; i < 4; ++i) {
                ushort4 o;
                o.x = f2bf(acc[i][0]); o.y = f2bf(acc[i][1]);
                o.z = f2bf(acc[i][2]); o.w = f2bf(acc[i][3]);
                *(ushort4*)(U + h * 65536 + (o0 + tm * 4 + i) * 256 + c0 + tn * 4) = o;
            }
        } else {                     // zero rs
            const int idx = ((wb - 224) * 256 + tid) * 4;
            *(float4*)(rs + idx) = make_float4(0.f, 0.f, 0.f, 0.f);
        }
    }
}

// -------- MFMA gemm_bt: C[m][n] = sum_k A[m][k] * B[n][k]  (bf16 in) -------
// 128x128 tile, BK=64 (two [128][32] sub-tiles), LDS-staged coalesced epilogue.
// MODE 0: C bf16 (k5). MODE 1: C f32 + bias (k6). MODE 3: kM. MODE 4: k3G
// split-K f32 partials. MODE 5: k1 Kexp=exp(acc) + rowsum atomics.
template<int MODE>
__global__ __launch_bounds__(256) void mfma_bt(
    const unsigned short* __restrict__ A0, int lda,
    const unsigned short* __restrict__ B0, int ldb,
    void* __restrict__ C0, int ldc,
    const float* __restrict__ bias, int Kp,
    unsigned long long sAz, unsigned long long sBz, unsigned long long sCz,
    float* __restrict__ aux)
{
    __shared__ __align__(16) unsigned char smem[67584];  // staging 32KB ∪ C-tile
    unsigned short* As = (unsigned short*)smem;            // 2 x [128][32]
    unsigned short* Bs = (unsigned short*)(smem + 16384);
    float (*CS)[132] = (float(*)[132])smem;                // epilogue alias

    const int tid  = threadIdx.x;
    const int w    = tid >> 6, lane = tid & 63;
    const int quad = lane >> 4, l16 = lane & 15;
    const int wm = (w >> 1) * 64, wn = (w & 1) * 64;
    const int z = blockIdx.z;

    const unsigned short* A;
    const unsigned short* B;
    int ks, ke, m0, n0;
    if constexpr (MODE == 3) {
        m0 = blockIdx.y * 128; n0 = 0;
        ks = 0; ke = 256;
        A = A0 + (unsigned long long)(z & 3) * 65536ull + (unsigned long long)m0 * lda;
        B = B0 + (unsigned long long)(z >> 2) * 131072ull + (unsigned long long)(z & 3) * 32768ull;
    } else if constexpr (MODE == 4) {
        m0 = blockIdx.y * 128; n0 = (blockIdx.x & 1) * 128;
        ks = (blockIdx.x >> 1) * 1024; ke = ks + 1024;
        A = A0 + sAz * z + (unsigned long long)m0 * lda;
        B = B0 + sBz * z + (unsigned long long)n0 * ldb;
    } else {
        m0 = blockIdx.y * 128; n0 = blockIdx.x * 128;
        ks = 0; ke = Kp;
        A = A0 + sAz * z + (unsigned long long)m0 * lda;
        B = B0 + sBz * z + (unsigned long long)n0 * ldb;
    }

    // staging: 1024 chunks of 16B per operand tile; chunk q: sub s=q>>9,
    // row r=(q>>2)&127, koff=(q&3)*8 + s*32; LDS dest = q*16B (lane-linear).
    const unsigned short* gA[4];
    const unsigned short* gB[4];
    int lo[4];
    #pragma unroll
    for (int i = 0; i < 4; ++i) {
        const int q = i * 256 + w * 64 + lane;
        const int s = q >> 9, r = (q >> 2) & 127, ko = (q & 3) * 8 + s * 32;
        gA[i] = A + (unsigned long long)r * lda + ko;
        gB[i] = B + (unsigned long long)r * ldb + ko;
        lo[i] = q * 8;
    }

    f32x4 acc[4][4] = {};

    for (int k0 = ks; k0 < ke; k0 += 64) {
        #pragma unroll
        for (int i = 0; i < 4; ++i) {
            gl_lds16(gA[i] + k0, As + lo[i]);
            gl_lds16(gB[i] + k0, Bs + lo[i]);
        }
        __syncthreads();
        #pragma unroll
        for (int s = 0; s < 2; ++s) {
            frag8 a[4], b[4];
            #pragma unroll
            for (int t = 0; t < 4; ++t) {
                a[t] = *(const frag8*)(As + s * 4096 + (wm + t * 16 + l16) * 32 + quad * 8);
                b[t] = *(const frag8*)(Bs + s * 4096 + (wn + t * 16 + l16) * 32 + quad * 8);
            }
            #pragma unroll
            for (int mt = 0; mt < 4; ++mt)
                #pragma unroll
                for (int nt = 0; nt < 4; ++nt)
                    acc[mt][nt] = __builtin_amdgcn_mfma_f32_16x16x32_bf16(
                        a[mt], b[nt], acc[mt][nt], 0, 0, 0);
        }
        __syncthreads();
    }

    // ---- epilogue: stage C-tile (f32) into LDS, then coalesced write-out ---
    // C/D mapping col = lane&15, row = quad*4 + reg  [m91-verified]
    if constexpr (MODE == 5) {
        float rp[4][4] = {};
        #pragma unroll
        for (int mt = 0; mt < 4; ++mt) {
            const int row = wm + mt * 16 + quad * 4;
            #pragma unroll
            for (int nt = 0; nt < 4; ++nt) {
                const int col = wn + nt * 16 + l16;
                #pragma unroll
                for (int r = 0; r < 4; ++r) {
                    const float e = __expf(acc[mt][nt][r]);
                    CS[row + r][col] = e;
                    rp[mt][r] += e;
                }
            }
        }
        #pragma unroll
        for (int m = 1; m < 16; m <<= 1)
            #pragma unroll
            for (int mt = 0; mt < 4; ++mt)
                #pragma unroll
                for (int r = 0; r < 4; ++r)
                    rp[mt][r] += __shfl_xor(rp[mt][r], m, 64);
        if (l16 == 0) {
            float* rsb = aux + z * 512 + m0;
            #pragma unroll
            for (int mt = 0; mt < 4; ++mt)
                #pragma unroll
                for (int r = 0; r < 4; ++r)
                    atomicAdd(rsb + wm + mt * 16 + quad * 4 + r, rp[mt][r]);
        }
    } else {
        #pragma unroll
        for (int mt = 0; mt < 4; ++mt) {
            const int row = wm + mt * 16 + quad * 4;
            #pragma unroll
            for (int nt = 0; nt < 4; ++nt) {
                const int col = wn + nt * 16 + l16;
                #pragma unroll
                for (int r = 0; r < 4; ++r)
                    CS[row + r][col] = acc[mt][nt][r];
            }
        }
    }
    __syncthreads();

    if constexpr (MODE == 1 || MODE == 4) {           // f32 out, 512B rows
        float* C;
        if constexpr (MODE == 1)
            C = (float*)C0 + sCz * z + (unsigned long long)m0 * ldc + n0;
        else
            C = (float*)C0 + (unsigned long long)(blockIdx.x >> 1) * 1048576ull
              + sCz * z + (unsigned long long)m0 * ldc + n0;
        const int lr0 = tid >> 5, c4 = (tid & 31) * 4;
        #pragma unroll
        for (int p = 0; p < 16; ++p) {
            const int lr = lr0 + p * 8;
            float4 v = *(const float4*)&CS[lr][c4];
            if constexpr (MODE == 1) {
                const float bv = bias[m0 + lr];
                v.x += bv; v.y += bv; v.z += bv; v.w += bv;
            }
            *(float4*)(C + (unsigned long long)lr * ldc + c4) = v;
        }
    } else {                                           // bf16 out, 256B rows
        unsigned short* C;
        if constexpr (MODE == 3)
            C = (unsigned short*)C0 + (unsigned long long)(z >> 2) * 131072ull
              + (unsigned long long)(z & 3) * 128ull + (unsigned long long)m0 * ldc;
        else
            C = (unsigned short*)C0 + sCz * z + (unsigned long long)m0 * ldc + n0;
        const int lr0 = tid >> 4, c8 = (tid & 15) * 8;
        #pragma unroll
        for (int p = 0; p < 8; ++p) {
            const int lr = lr0 + p * 16;
            us8 o;
            #pragma unroll
            for (int j = 0; j < 8; ++j) o[j] = f2bf(CS[lr][c8 + j]);
            *(us8*)(C + (unsigned long long)lr * ldc + c8) = o;
        }
    }
}

// ------- k3_sum: G[i] = bf16( (sum_s Gp[s][i]) / rs[row] ), i < 1048576 ----
__global__ __launch_bounds__(256) void k3_sum(
    const float* __restrict__ Gp, const float* __restrict__ rs,
    unsigned short* __restrict__ G)
{
    const int idx = (blockIdx.x * 256 + threadIdx.x) * 4;
    const float inv = 1.0f / rs[idx >> 8];
    float4 s = make_float4(0.f, 0.f, 0.f, 0.f);
    #pragma unroll
    for (int sl = 0; sl < 4; ++sl) {
        float4 t = *(const float4*)(Gp + (size_t)sl * 1048576 + idx);
        s.x += t.x; s.y += t.y; s.z += t.z; s.w += t.w;
    }
    ushort4 o;
    o.x = f2bf(s.x * inv); o.y = f2bf(s.y * inv);
    o.z = f2bf(s.z * inv); o.w = f2bf(s.w * inv);
    *(ushort4*)(G + idx) = o;
}

extern "C" void kernel_launch(void* const* d_in, const int* in_sizes, int n_in,
                              void* d_out, int out_size, void* d_ws, size_t ws_size,
                              hipStream_t stream) {
    (void)in_sizes; (void)n_in; (void)out_size; (void)ws_size;
    const float* x     = (const float*)d_in[0];  // f32 [8,256,64,64]
    const float* w_qkv = (const float*)d_in[1];  // f32 [1536,256]
    const float* w_out = (const float*)d_in[2];  // f32 [256,512]
    const float* b_out = (const float*)d_in[3];  // f32 [256]
    float* out = (float*)d_out;                  // f32 [8,256,64,64]

    char* ws = (char*)d_ws;
    unsigned short* Kexp = (unsigned short*)ws;                 // 33,554,432
    unsigned short* xbT  = (unsigned short*)(ws + 33554432);    // 16,777,216
    unsigned short* xbc  = (unsigned short*)(ws + 50331648);    // 16,777,216
    unsigned short* wkb  = (unsigned short*)(ws + 67108864);    //    262,144
    unsigned short* wqT  = (unsigned short*)(ws + 67371008);    //    262,144
    unsigned short* U    = (unsigned short*)(ws + 67633152);    //    524,288
    float*          rs   = (float*)(ws + 68157440);             //     16,384
    float*          Gp   = (float*)(ws + 68173824);             // 16,777,216
    unsigned short* G    = (unsigned short*)(ws + 84951040);    //  2,097,152
    unsigned short* Mb   = (unsigned short*)(ws + 87048192);    //  2,097,152
    unsigned short* Nb   = (unsigned short*)(ws + 89145344);    //  1,048,576

    k0_all<<<dim3(1252), 256, 0, stream>>>(x, w_qkv, w_out, xbT, xbc, wkb, wqT, U, rs);
    // k1: Kexp[b][r][n] = exp( sum_c wkb[r][c] * xbT[b][n][c] ), rs += rowsums
    mfma_bt<5><<<dim3(32, 4, 8), 256, 0, stream>>>(
        wkb, 256, xbT, 256, Kexp, 4096, nullptr, 256,
        0ull, 1048576ull, 2097152ull, rs);
    // k3G: Gp[ks][b][hd][c] = sum_{n in slice} Kexp[b][hd][n] * xbc[b][c][n]
    mfma_bt<4><<<dim3(8, 4, 8), 256, 0, stream>>>(
        Kexp, 4096, xbc, 4096, Gp, 256, nullptr, 0,
        2097152ull, 1048576ull, 131072ull, nullptr);
    k3_sum<<<dim3(1024), 256, 0, stream>>>(Gp, rs, G);
    // kM: Mb[b][o][h*128+d] = sum_c U[h][o][c] * G[b][h*128+d][c]
    mfma_bt<3><<<dim3(1, 2, 32), 256, 0, stream>>>(
        U, 256, G, 256, Mb, 512, nullptr, 256,
        0ull, 0ull, 0ull, nullptr);
    // k5: Nb[b][o][c] = sum_j Mb[b][o][j] * wqT[c][j]
    mfma_bt<0><<<dim3(2, 2, 8), 256, 0, stream>>>(
        Mb, 512, wqT, 512, Nb, 256, nullptr, 512,
        131072ull, 0ull, 65536ull, nullptr);
    // k6: out[b][o][n] = sum_c Nb[b][o][c] * xbT[b][n][c] + b_out[o]
    mfma_bt<1><<<dim3(32, 2, 8), 256, 0, stream>>>(
        Nb, 256, xbT, 256, out, 4096, b_out, 256,
        65536ull, 1048576ull, 1048576ull, nullptr);
}